// Round 6
// baseline (493.458 us; speedup 1.0000x reference)
//
#include <hip/hip_runtime.h>

constexpr int kNR = 40000;
constexpr int kNU = 30000;
constexpr int kNP = 30000;
constexpr int kN  = 100000;          // total nodes
constexpr int kE  = 1600000;         // edges
constexpr int kF  = 128;             // feature/hidden dim
constexpr int kC  = 40;              // classes
constexpr int kSB = 98;              // ceil(kN/1024) scan blocks
constexpr int kAS = 28;              // agg row stride (27 used, 112B rows)

// ---------- bf16 helpers (storage-only; math in fp32) ----------
__device__ __forceinline__ float bf_to_f(unsigned short h) {
    union { unsigned int i; float f; } u; u.i = ((unsigned int)h) << 16; return u.f;
}
__device__ __forceinline__ unsigned short f_to_bf(float f) {
    union { unsigned int i; float f; } u; u.f = f;
    unsigned int r = u.i + 0x7FFFu + ((u.i >> 16) & 1u);   // round-nearest-even
    return (unsigned short)(r >> 16);
}
__device__ __forceinline__ float2 bf2_to_f2(unsigned int p) {
    union { unsigned int i; float f; } lo, hi;
    lo.i = (p & 0xFFFFu) << 16;
    hi.i = p & 0xFFFF0000u;
    return make_float2(lo.f, hi.f);
}
__device__ __forceinline__ unsigned int pack_bf2(float a, float b) {
    return (unsigned int)f_to_bf(a) | ((unsigned int)f_to_bf(b) << 16);
}
__device__ __forceinline__ float ldf(const void* p, int i, int isbf) {
    return isbf ? bf_to_f(((const unsigned short*)p)[i]) : ((const float*)p)[i];
}
__device__ __forceinline__ int lde(const int* p, int i, int is64) {
    return is64 ? p[2 * i] : p[i];
}

// ---------- sniff dtypes -> flags[0]=isbf, flags[1]=is64 ----------
__global__ void gcn_sniff(const unsigned int* __restrict__ w1w,
                          const int* __restrict__ eiw, int* __restrict__ flags) {
    if (blockIdx.x != 0 || threadIdx.x != 0) return;
    int plaus = 0;
    for (int k = 0; k < 64; k++) {
        unsigned int ax = w1w[k] & 0x7FFFu;
        plaus += (ax == 0u) || (ax > 0x2000u && ax < 0x4000u);
    }
    flags[0] = (plaus >= 48) ? 1 : 0;
    int nz = 0;
    for (int k = 0; k < 64; k++) nz |= eiw[2 * k + 1];
    flags[1] = (nz == 0) ? 1 : 0;
}

__global__ void gcn_zero_i32(int* __restrict__ p, int n) {
    int i = blockIdx.x * 256 + threadIdx.x;
    if (i < n) p[i] = 0;
}

// ---------- fused weights fw27[27][128] fp32 ----------
// rows 0-4: Wr@W1 (5-7 zero) | 8-14: Wu@W1 (15 zero) | 16-21: Wp@W1 (22-23 zero)
// rows 24/25/26: br@W1 / bu@W1 / bp@W1
__global__ void gcn_fuse(const void* __restrict__ Wr, const void* __restrict__ br,
                         const void* __restrict__ Wu, const void* __restrict__ bu,
                         const void* __restrict__ Wp, const void* __restrict__ bp,
                         const void* __restrict__ W1, float* __restrict__ fw27,
                         const int* __restrict__ flags) {
    __shared__ float sw[21 * kF];    // rows 0-4 Wr, 5-11 Wu, 12-17 Wp, 18 br, 19 bu, 20 bp
    int isbf = flags[0];
    int t = threadIdx.x;             // 128 threads
    for (int i = t; i < 21 * kF; i += 128) {
        int r = i >> 7, c = i & 127;
        float v;
        if (r < 5)        v = ldf(Wr, r * kF + c, isbf);
        else if (r < 12)  v = ldf(Wu, (r - 5) * kF + c, isbf);
        else if (r < 18)  v = ldf(Wp, (r - 12) * kF + c, isbf);
        else if (r == 18) v = ldf(br, c, isbf);
        else if (r == 19) v = ldf(bu, c, isbf);
        else              v = ldf(bp, c, isbf);
        sw[i] = v;
    }
    __syncthreads();
    int j = t;                       // output column of W1
    float acc[21];
    #pragma unroll
    for (int r = 0; r < 21; r++) acc[r] = 0.f;
    for (int k = 0; k < kF; k++) {
        float w1 = ldf(W1, k * kF + j, isbf);    // coalesced across j
        #pragma unroll
        for (int r = 0; r < 21; r++) acc[r] += sw[r * kF + k] * w1;  // LDS broadcast
    }
    #pragma unroll
    for (int r = 0; r < 27; r++) fw27[r * kF + j] = 0.f;
    #pragma unroll
    for (int i = 0; i < 5; i++) fw27[(0  + i)*kF + j] = acc[i];       // R slots
    #pragma unroll
    for (int i = 0; i < 7; i++) fw27[(8  + i)*kF + j] = acc[5 + i];   // U slots
    #pragma unroll
    for (int i = 0; i < 6; i++) fw27[(16 + i)*kF + j] = acc[12 + i];  // P slots
    fw27[24*kF + j] = acc[18];  fw27[25*kF + j] = acc[19];  fw27[26*kF + j] = acc[20];
}

// ---------- pack raw features: xpack[n] = uint4 of 8 bf16 (zero-padded) ----------
__global__ void __launch_bounds__(256) gcn_pack(const void* __restrict__ xr,
                                                const void* __restrict__ xu,
                                                const void* __restrict__ xp,
                                                uint4* __restrict__ xpack,
                                                const int* __restrict__ flags) {
    int isbf = flags[0];
    int n = blockIdx.x * 256 + threadIdx.x;
    if (n >= kN) return;
    const void* base; int roff, d;
    if (n < kNR)            { base = xr; roff = n * 5;               d = 5; }
    else if (n < kNR + kNU) { base = xu; roff = (n - kNR) * 7;       d = 7; }
    else                    { base = xp; roff = (n - kNR - kNU) * 6; d = 6; }
    float f[8];
    #pragma unroll
    for (int i = 0; i < 8; i++) f[i] = (i < d) ? ldf(base, roff + i, isbf) : 0.f;
    uint4 u;
    u.x = pack_bf2(f[0], f[1]);  u.y = pack_bf2(f[2], f[3]);
    u.z = pack_bf2(f[4], f[5]);  u.w = pack_bf2(f[6], f[7]);
    xpack[n] = u;
}

// ---------- CSR build ----------
__global__ void gcn_hist(const int* __restrict__ ei, int* __restrict__ cnt,
                         const int* __restrict__ flags) {
    int is64 = flags[1];
    int e = blockIdx.x * 256 + threadIdx.x;
    if (e < kE) {
        unsigned int d = (unsigned int)lde(ei, kE + e, is64);
        if (d < (unsigned int)kN) atomicAdd(&cnt[d], 1);
    }
}

__global__ void gcn_scan1(const int* __restrict__ cnt, int* __restrict__ bsums) {
    __shared__ int lds[256];
    int t = threadIdx.x;
    int base = blockIdx.x * 1024 + t * 4;
    int s = 0;
    #pragma unroll
    for (int j = 0; j < 4; j++) { int i = base + j; s += (i < kN) ? cnt[i] : 0; }
    lds[t] = s; __syncthreads();
    for (int o = 128; o > 0; o >>= 1) {
        if (t < o) lds[t] += lds[t + o];
        __syncthreads();
    }
    if (t == 0) bsums[blockIdx.x] = lds[0];
}

__global__ void gcn_scan2(int* __restrict__ bsums, int* __restrict__ rp) {
    __shared__ int lds[128];
    int t = threadIdx.x;
    int v = (t < kSB) ? bsums[t] : 0;
    int incl = v; lds[t] = incl; __syncthreads();
    for (int o = 1; o < 128; o <<= 1) {
        int y = (t >= o) ? lds[t - o] : 0;
        __syncthreads();
        incl += y; lds[t] = incl;
        __syncthreads();
    }
    if (t < kSB) bsums[t] = incl - v;
    if (t == 127) rp[kN] = incl;
}

__global__ void gcn_scan3(const int* __restrict__ cnt, const int* __restrict__ bsums,
                          int* __restrict__ rp, int* __restrict__ cur) {
    __shared__ int lds[256];
    int t = threadIdx.x;
    int base = blockIdx.x * 1024 + t * 4;
    int v0 = (base + 0 < kN) ? cnt[base + 0] : 0;
    int v1 = (base + 1 < kN) ? cnt[base + 1] : 0;
    int v2 = (base + 2 < kN) ? cnt[base + 2] : 0;
    int v3 = (base + 3 < kN) ? cnt[base + 3] : 0;
    int s = v0 + v1 + v2 + v3;
    int incl = s; lds[t] = incl; __syncthreads();
    for (int o = 1; o < 256; o <<= 1) {
        int y = (t >= o) ? lds[t - o] : 0;
        __syncthreads();
        incl += y; lds[t] = incl;
        __syncthreads();
    }
    int excl = incl - s + bsums[blockIdx.x];
    if (base + 0 < kN) { rp[base + 0] = excl; cur[base + 0] = excl; }  excl += v0;
    if (base + 1 < kN) { rp[base + 1] = excl; cur[base + 1] = excl; }  excl += v1;
    if (base + 2 < kN) { rp[base + 2] = excl; cur[base + 2] = excl; }  excl += v2;
    if (base + 3 < kN) { rp[base + 3] = excl; cur[base + 3] = excl; }
}

// ---------- fill, XCD-localized (R5: WRITE 105MB -> full-line evictions) ----------
__global__ void __launch_bounds__(256) gcn_fill(const int* __restrict__ ei,
                                                int* __restrict__ cur,
                                                int* __restrict__ col,
                                                const int* __restrict__ flags) {
    int is64 = flags[1];
    int r  = blockIdx.x & 7;                 // XCD slot (heuristic)
    int vb = blockIdx.x >> 3;                // virtual block within group: 0..255
    int lo = r * (kN / 8);
    int hi = lo + (kN / 8);
    const int gthreads = 256 * 256;
    for (int e = vb * 256 + (int)threadIdx.x; e < kE; e += gthreads) {
        int d = lde(ei, kE + e, is64);
        if (d >= lo && d < hi) {
            int p = atomicAdd(&cur[d], 1);
            unsigned int s = (unsigned int)lde(ei, e, is64);
            if ((unsigned int)p < (unsigned int)kE)
                col[p] = (s < (unsigned int)kN) ? (int)s : 0;
        }
    }
}

// ---------- layer-1 RAW gather: thread-per-dst, 16B/edge from L2-resident 1.6MB table ----------
// agg27 = [accR(8), accU(8), accP(8), cntR, cntU, cntP]; then A@(xW1) = agg27 @ fw27.
__global__ void __launch_bounds__(256) GCN_2190433321521_kernel(
        const uint4* __restrict__ xpack,
        const int* __restrict__ rp,
        const int* __restrict__ col,
        float* __restrict__ agg) {
    int n = blockIdx.x * 256 + threadIdx.x;
    if (n >= kN) return;
    int beg = rp[n], end = rp[n + 1];
    float aR[8], aU[8], aP[8];
    #pragma unroll
    for (int i = 0; i < 8; i++) { aR[i] = 0.f; aU[i] = 0.f; aP[i] = 0.f; }
    float cR = 0.f, cU = 0.f, cP = 0.f;

    auto acc1 = [&](int s, uint4 u) {
        float2 p0 = bf2_to_f2(u.x), p1 = bf2_to_f2(u.y);
        float2 p2 = bf2_to_f2(u.z), p3 = bf2_to_f2(u.w);
        if (s < kNR) {
            aR[0]+=p0.x; aR[1]+=p0.y; aR[2]+=p1.x; aR[3]+=p1.y;
            aR[4]+=p2.x; aR[5]+=p2.y; aR[6]+=p3.x; aR[7]+=p3.y; cR += 1.f;
        } else if (s < kNR + kNU) {
            aU[0]+=p0.x; aU[1]+=p0.y; aU[2]+=p1.x; aU[3]+=p1.y;
            aU[4]+=p2.x; aU[5]+=p2.y; aU[6]+=p3.x; aU[7]+=p3.y; cU += 1.f;
        } else {
            aP[0]+=p0.x; aP[1]+=p0.y; aP[2]+=p1.x; aP[3]+=p1.y;
            aP[4]+=p2.x; aP[5]+=p2.y; aP[6]+=p3.x; aP[7]+=p3.y; cP += 1.f;
        }
    };
    int e = beg;
    for (; e + 1 < end; e += 2) {            // 2 uint4 loads in flight
        int s0 = col[e], s1 = col[e + 1];
        uint4 u0 = xpack[s0];
        uint4 u1 = xpack[s1];
        acc1(s0, u0);
        acc1(s1, u1);
    }
    if (e < end) { int s0 = col[e]; acc1(s0, xpack[s0]); }

    float* o = agg + (size_t)n * kAS;
    #pragma unroll
    for (int i = 0; i < 8; i++) o[i]      = aR[i];
    #pragma unroll
    for (int i = 0; i < 8; i++) o[8 + i]  = aU[i];
    #pragma unroll
    for (int i = 0; i < 8; i++) o[16 + i] = aP[i];
    o[24] = cR;  o[25] = cU;  o[26] = cP;
}

// ---------- dense: h = relu(agg27 @ fw27); hw = h @ W2. Wave-per-node. ----------
__global__ void __launch_bounds__(256) gcn_dense(const float* __restrict__ agg,
                                                 const float* __restrict__ fw27,
                                                 const void* __restrict__ W2,
                                                 unsigned short* __restrict__ hw,
                                                 const int* __restrict__ flags) {
    __shared__ float fwl[27 * kF];   // 13.5 KB
    __shared__ float w2f[kF * kC];   // 20 KB
    __shared__ float hrow[4][kF];    // 2 KB
    int isbf = flags[0];
    for (int i = threadIdx.x; i < 27 * kF; i += 256) fwl[i] = fw27[i];
    for (int i = threadIdx.x; i < kF * kC; i += 256) w2f[i] = ldf(W2, i, isbf);
    __syncthreads();
    int lane = threadIdx.x & 63;
    int wid  = threadIdx.x >> 6;
    float* hr = hrow[wid];
    int f0 = 2 * lane;
    int stride = gridDim.x * 4;
    for (int n = blockIdx.x * 4 + wid; n < kN; n += stride) {
        float av = (lane < 27) ? agg[(size_t)n * kAS + lane] : 0.f;
        float a0 = 0.f, a1 = 0.f;
        #pragma unroll
        for (int k = 0; k < 27; k++) {
            float a = __shfl(av, k, 64);
            a0 += a * fwl[k * kF + f0];
            a1 += a * fwl[k * kF + f0 + 1];
        }
        hr[f0]     = fmaxf(a0, 0.f);     // same-wave LDS: ordered, no barrier
        hr[f0 + 1] = fmaxf(a1, 0.f);
        if (lane < kC) {
            float acc = 0.f;
            #pragma unroll 8
            for (int k = 0; k < kF; k++)
                acc += hr[k] * w2f[k * kC + lane];
            hw[(size_t)n * kC + lane] = f_to_bf(acc);
        }
    }
}

// ---------- layer-2 gather: 3 edge-groups x 20 class-lanes per wave ----------
__global__ void __launch_bounds__(256) gcn_gather2(const unsigned int* __restrict__ hw32,
                                                   const int* __restrict__ rp,
                                                   const int* __restrict__ col,
                                                   unsigned int* __restrict__ out,
                                                   const int* __restrict__ flags) {
    int isbf = flags[0];
    int w = (blockIdx.x * 256 + threadIdx.x) >> 6;
    if (w >= kN) return;
    int lane = threadIdx.x & 63;
    int grp = lane / 20;          // 0..2 active, 3 idle
    int c2  = lane % 20;          // class pair
    int beg = rp[w], end = rp[w + 1];
    float ax = 0.f, ay = 0.f;
    if (grp < 3) {
        int e = beg + grp;
        for (; e + 3 < end; e += 6) {        // 2 loads in flight per group
            float2 f0 = bf2_to_f2(hw32[col[e]     * 20 + c2]);
            float2 f1 = bf2_to_f2(hw32[col[e + 3] * 20 + c2]);
            ax += f0.x + f1.x;  ay += f0.y + f1.y;
        }
        if (e < end) {
            float2 f = bf2_to_f2(hw32[col[e] * 20 + c2]);
            ax += f.x; ay += f.y;
        }
    }
    ax += __shfl(ax, lane + 20, 64) + __shfl(ax, lane + 40, 64);
    ay += __shfl(ay, lane + 20, 64) + __shfl(ay, lane + 40, 64);
    if (lane < 20) {
        if (isbf) {
            out[w * 20 + lane] = pack_bf2(ax, ay);
        } else {
            float* of = (float*)out;
            of[w * 40 + 2*lane]     = ax;
            of[w * 40 + 2*lane + 1] = ay;
        }
    }
}

extern "C" void kernel_launch(void* const* d_in, const int* in_sizes, int n_in,
                              void* d_out, int out_size, void* d_ws, size_t ws_size,
                              hipStream_t stream) {
    const void* xr = d_in[0];
    const void* xu = d_in[1];
    const void* xp = d_in[2];
    const int*  ei = (const int*)d_in[3];
    const void* Wr = d_in[4];
    const void* br = d_in[5];
    const void* Wu = d_in[6];
    const void* bu = d_in[7];
    const void* Wp = d_in[8];
    const void* bp = d_in[9];
    const void* W1 = d_in[10];
    const void* W2 = d_in[11];
    (void)in_sizes; (void)n_in; (void)out_size; (void)ws_size;

    char* ws = (char*)d_ws;
    size_t off = 0;
    auto alloc = [&](size_t bytes) -> void* {
        void* p = (void*)(ws + off);
        off = (off + bytes + 255) & ~(size_t)255;
        return p;
    };
    int*            flags = (int*)           alloc(256);
    int*            rp    = (int*)           alloc((size_t)(kN + 1) * 4);
    int*            cnt   = (int*)           alloc((size_t)kN * 4);
    int*            cur   = (int*)           alloc((size_t)kN * 4);
    int*            bs    = (int*)           alloc(128 * 4);
    float*          fw27  = (float*)         alloc(27 * kF * 4);
    uint4*          xpack = (uint4*)         alloc((size_t)kN * 16);        // 1.6 MB
    int*            col   = (int*)           alloc((size_t)kE * 4);         // 6.4 MB
    unsigned short* hwb   = (unsigned short*)alloc((size_t)kN * kC * 2);    // 8 MB bf16
    float*          agg   = (float*)         alloc((size_t)kN * kAS * 4);   // 11.2 MB

    gcn_sniff<<<1, 64, 0, stream>>>((const unsigned int*)W1, ei, flags);
    gcn_zero_i32<<<(kN + 255) / 256, 256, 0, stream>>>(cnt, kN);
    gcn_fuse<<<1, 128, 0, stream>>>(Wr, br, Wu, bu, Wp, bp, W1, fw27, flags);
    gcn_pack<<<(kN + 255) / 256, 256, 0, stream>>>(xr, xu, xp, xpack, flags);
    gcn_hist<<<(kE + 255) / 256, 256, 0, stream>>>(ei, cnt, flags);
    gcn_scan1<<<kSB, 256, 0, stream>>>(cnt, bs);
    gcn_scan2<<<1, 128, 0, stream>>>(bs, rp);
    gcn_scan3<<<kSB, 256, 0, stream>>>(cnt, bs, rp, cur);
    gcn_fill<<<2048, 256, 0, stream>>>(ei, cur, col, flags);
    GCN_2190433321521_kernel<<<(kN + 255) / 256, 256, 0, stream>>>(xpack, rp, col, agg);
    gcn_dense<<<1024, 256, 0, stream>>>(agg, fw27, W2, hwb, flags);
    gcn_gather2<<<(kN * 64 + 255) / 256, 256, 0, stream>>>((const unsigned int*)hwb, rp, col,
                                                           (unsigned int*)d_out, flags);
}

// Round 7
// 407.135 us; speedup vs baseline: 1.2120x; 1.2120x over previous
//
#include <hip/hip_runtime.h>

constexpr int kNR = 40000;
constexpr int kNU = 30000;
constexpr int kNP = 30000;
constexpr int kN  = 100000;          // total nodes
constexpr int kE  = 1600000;         // edges
constexpr int kF  = 128;             // feature/hidden dim
constexpr int kC  = 40;              // classes
constexpr int kSB = 98;              // ceil(kN/1024) scan blocks
constexpr int kAS = 32;              // agg row stride (27 used; 128B rows for dwordx4)

typedef __attribute__((ext_vector_type(8))) short bf16x8;   // 4 VGPRs: MFMA A/B frag
typedef __attribute__((ext_vector_type(4))) float f32x4;    // MFMA C/D frag

// ---------- bf16 helpers (storage-only; math in fp32) ----------
__device__ __forceinline__ float bf_to_f(unsigned short h) {
    union { unsigned int i; float f; } u; u.i = ((unsigned int)h) << 16; return u.f;
}
__device__ __forceinline__ unsigned short f_to_bf(float f) {
    union { unsigned int i; float f; } u; u.f = f;
    unsigned int r = u.i + 0x7FFFu + ((u.i >> 16) & 1u);   // round-nearest-even
    return (unsigned short)(r >> 16);
}
__device__ __forceinline__ float2 bf2_to_f2(unsigned int p) {
    union { unsigned int i; float f; } lo, hi;
    lo.i = (p & 0xFFFFu) << 16;
    hi.i = p & 0xFFFF0000u;
    return make_float2(lo.f, hi.f);
}
__device__ __forceinline__ unsigned int pack_bf2(float a, float b) {
    return (unsigned int)f_to_bf(a) | ((unsigned int)f_to_bf(b) << 16);
}
__device__ __forceinline__ float ldf(const void* p, int i, int isbf) {
    return isbf ? bf_to_f(((const unsigned short*)p)[i]) : ((const float*)p)[i];
}
__device__ __forceinline__ int lde(const int* p, int i, int is64) {
    return is64 ? p[2 * i] : p[i];
}

// ---------- sniff dtypes -> flags[0]=isbf, flags[1]=is64 ----------
__global__ void gcn_sniff(const unsigned int* __restrict__ w1w,
                          const int* __restrict__ eiw, int* __restrict__ flags) {
    if (blockIdx.x != 0 || threadIdx.x != 0) return;
    int plaus = 0;
    for (int k = 0; k < 64; k++) {
        unsigned int ax = w1w[k] & 0x7FFFu;
        plaus += (ax == 0u) || (ax > 0x2000u && ax < 0x4000u);
    }
    flags[0] = (plaus >= 48) ? 1 : 0;
    int nz = 0;
    for (int k = 0; k < 64; k++) nz |= eiw[2 * k + 1];
    flags[1] = (nz == 0) ? 1 : 0;
}

__global__ void gcn_zero_i32(int* __restrict__ p, int n) {
    int i = blockIdx.x * 256 + threadIdx.x;
    if (i < n) p[i] = 0;
}

// ---------- fused weights, emitted TRANSPOSED bf16: fwT[feat(128)][slot(32)] ----------
// slots 0-4: Wr@W1 | 8-14: Wu@W1 | 16-21: Wp@W1 | 24/25/26: br/bu/bp @W1 | rest 0
__global__ void gcn_fuse(const void* __restrict__ Wr, const void* __restrict__ br,
                         const void* __restrict__ Wu, const void* __restrict__ bu,
                         const void* __restrict__ Wp, const void* __restrict__ bp,
                         const void* __restrict__ W1, unsigned short* __restrict__ fwT,
                         const int* __restrict__ flags) {
    __shared__ float sw[21 * kF];    // rows 0-4 Wr, 5-11 Wu, 12-17 Wp, 18 br, 19 bu, 20 bp
    int isbf = flags[0];
    int t = threadIdx.x;             // 128 threads
    for (int i = t; i < 21 * kF; i += 128) {
        int r = i >> 7, c = i & 127;
        float v;
        if (r < 5)        v = ldf(Wr, r * kF + c, isbf);
        else if (r < 12)  v = ldf(Wu, (r - 5) * kF + c, isbf);
        else if (r < 18)  v = ldf(Wp, (r - 12) * kF + c, isbf);
        else if (r == 18) v = ldf(br, c, isbf);
        else if (r == 19) v = ldf(bu, c, isbf);
        else              v = ldf(bp, c, isbf);
        sw[i] = v;
    }
    __syncthreads();
    int j = t;                       // output column (feature) of W1
    float acc[21];
    #pragma unroll
    for (int r = 0; r < 21; r++) acc[r] = 0.f;
    for (int k = 0; k < kF; k++) {
        float w1 = ldf(W1, k * kF + j, isbf);    // coalesced across j
        #pragma unroll
        for (int r = 0; r < 21; r++) acc[r] += sw[r * kF + k] * w1;  // LDS broadcast
    }
    unsigned short row[32];
    #pragma unroll
    for (int s = 0; s < 32; s++) row[s] = 0;
    #pragma unroll
    for (int i = 0; i < 5; i++) row[0  + i] = f_to_bf(acc[i]);
    #pragma unroll
    for (int i = 0; i < 7; i++) row[8  + i] = f_to_bf(acc[5 + i]);
    #pragma unroll
    for (int i = 0; i < 6; i++) row[16 + i] = f_to_bf(acc[12 + i]);
    row[24] = f_to_bf(acc[18]);  row[25] = f_to_bf(acc[19]);  row[26] = f_to_bf(acc[20]);
    #pragma unroll
    for (int s = 0; s < 32; s++) fwT[j * 32 + s] = row[s];
}

// ---------- pack raw features: xpack[n] = uint4 of 8 bf16 (zero-padded) ----------
__global__ void __launch_bounds__(256) gcn_pack(const void* __restrict__ xr,
                                                const void* __restrict__ xu,
                                                const void* __restrict__ xp,
                                                uint4* __restrict__ xpack,
                                                const int* __restrict__ flags) {
    int isbf = flags[0];
    int n = blockIdx.x * 256 + threadIdx.x;
    if (n >= kN) return;
    const void* base; int roff, d;
    if (n < kNR)            { base = xr; roff = n * 5;               d = 5; }
    else if (n < kNR + kNU) { base = xu; roff = (n - kNR) * 7;       d = 7; }
    else                    { base = xp; roff = (n - kNR - kNU) * 6; d = 6; }
    float f[8];
    #pragma unroll
    for (int i = 0; i < 8; i++) f[i] = (i < d) ? ldf(base, roff + i, isbf) : 0.f;
    uint4 u;
    u.x = pack_bf2(f[0], f[1]);  u.y = pack_bf2(f[2], f[3]);
    u.z = pack_bf2(f[4], f[5]);  u.w = pack_bf2(f[6], f[7]);
    xpack[n] = u;
}

// ---------- CSR build ----------
__global__ void gcn_hist(const int* __restrict__ ei, int* __restrict__ cnt,
                         const int* __restrict__ flags) {
    int is64 = flags[1];
    int e = blockIdx.x * 256 + threadIdx.x;
    if (e < kE) {
        unsigned int d = (unsigned int)lde(ei, kE + e, is64);
        if (d < (unsigned int)kN) atomicAdd(&cnt[d], 1);
    }
}

__global__ void gcn_scan1(const int* __restrict__ cnt, int* __restrict__ bsums) {
    __shared__ int lds[256];
    int t = threadIdx.x;
    int base = blockIdx.x * 1024 + t * 4;
    int s = 0;
    #pragma unroll
    for (int j = 0; j < 4; j++) { int i = base + j; s += (i < kN) ? cnt[i] : 0; }
    lds[t] = s; __syncthreads();
    for (int o = 128; o > 0; o >>= 1) {
        if (t < o) lds[t] += lds[t + o];
        __syncthreads();
    }
    if (t == 0) bsums[blockIdx.x] = lds[0];
}

__global__ void gcn_scan2(int* __restrict__ bsums, int* __restrict__ rp) {
    __shared__ int lds[128];
    int t = threadIdx.x;
    int v = (t < kSB) ? bsums[t] : 0;
    int incl = v; lds[t] = incl; __syncthreads();
    for (int o = 1; o < 128; o <<= 1) {
        int y = (t >= o) ? lds[t - o] : 0;
        __syncthreads();
        incl += y; lds[t] = incl;
        __syncthreads();
    }
    if (t < kSB) bsums[t] = incl - v;
    if (t == 127) rp[kN] = incl;
}

__global__ void gcn_scan3(const int* __restrict__ cnt, const int* __restrict__ bsums,
                          int* __restrict__ rp, int* __restrict__ cur) {
    __shared__ int lds[256];
    int t = threadIdx.x;
    int base = blockIdx.x * 1024 + t * 4;
    int v0 = (base + 0 < kN) ? cnt[base + 0] : 0;
    int v1 = (base + 1 < kN) ? cnt[base + 1] : 0;
    int v2 = (base + 2 < kN) ? cnt[base + 2] : 0;
    int v3 = (base + 3 < kN) ? cnt[base + 3] : 0;
    int s = v0 + v1 + v2 + v3;
    int incl = s; lds[t] = incl; __syncthreads();
    for (int o = 1; o < 256; o <<= 1) {
        int y = (t >= o) ? lds[t - o] : 0;
        __syncthreads();
        incl += y; lds[t] = incl;
        __syncthreads();
    }
    int excl = incl - s + bsums[blockIdx.x];
    if (base + 0 < kN) { rp[base + 0] = excl; cur[base + 0] = excl; }  excl += v0;
    if (base + 1 < kN) { rp[base + 1] = excl; cur[base + 1] = excl; }  excl += v1;
    if (base + 2 < kN) { rp[base + 2] = excl; cur[base + 2] = excl; }  excl += v2;
    if (base + 3 < kN) { rp[base + 3] = excl; cur[base + 3] = excl; }
}

// ---------- fill, XCD-localized (R5: full-line evictions) ----------
__global__ void __launch_bounds__(256) gcn_fill(const int* __restrict__ ei,
                                                int* __restrict__ cur,
                                                int* __restrict__ col,
                                                const int* __restrict__ flags) {
    int is64 = flags[1];
    int r  = blockIdx.x & 7;                 // XCD slot (heuristic)
    int vb = blockIdx.x >> 3;
    int lo = r * (kN / 8);
    int hi = lo + (kN / 8);
    const int gthreads = 256 * 256;
    for (int e = vb * 256 + (int)threadIdx.x; e < kE; e += gthreads) {
        int d = lde(ei, kE + e, is64);
        if (d >= lo && d < hi) {
            int p = atomicAdd(&cur[d], 1);
            unsigned int s = (unsigned int)lde(ei, e, is64);
            if ((unsigned int)p < (unsigned int)kE)
                col[p] = (s < (unsigned int)kN) ? (int)s : 0;
        }
    }
}

// ---------- layer-1 RAW gather: thread-per-dst, 16B/edge from L2-resident 1.6MB table ----------
__global__ void __launch_bounds__(256) GCN_2190433321521_kernel(
        const uint4* __restrict__ xpack,
        const int* __restrict__ rp,
        const int* __restrict__ col,
        float* __restrict__ agg) {
    int n = blockIdx.x * 256 + threadIdx.x;
    if (n >= kN) return;
    int beg = rp[n], end = rp[n + 1];
    float aR[8], aU[8], aP[8];
    #pragma unroll
    for (int i = 0; i < 8; i++) { aR[i] = 0.f; aU[i] = 0.f; aP[i] = 0.f; }
    float cR = 0.f, cU = 0.f, cP = 0.f;

    auto acc1 = [&](int s, uint4 u) {
        float2 p0 = bf2_to_f2(u.x), p1 = bf2_to_f2(u.y);
        float2 p2 = bf2_to_f2(u.z), p3 = bf2_to_f2(u.w);
        if (s < kNR) {
            aR[0]+=p0.x; aR[1]+=p0.y; aR[2]+=p1.x; aR[3]+=p1.y;
            aR[4]+=p2.x; aR[5]+=p2.y; aR[6]+=p3.x; aR[7]+=p3.y; cR += 1.f;
        } else if (s < kNR + kNU) {
            aU[0]+=p0.x; aU[1]+=p0.y; aU[2]+=p1.x; aU[3]+=p1.y;
            aU[4]+=p2.x; aU[5]+=p2.y; aU[6]+=p3.x; aU[7]+=p3.y; cU += 1.f;
        } else {
            aP[0]+=p0.x; aP[1]+=p0.y; aP[2]+=p1.x; aP[3]+=p1.y;
            aP[4]+=p2.x; aP[5]+=p2.y; aP[6]+=p3.x; aP[7]+=p3.y; cP += 1.f;
        }
    };
    int e = beg;
    for (; e + 1 < end; e += 2) {
        int s0 = col[e], s1 = col[e + 1];
        uint4 u0 = xpack[s0];
        uint4 u1 = xpack[s1];
        acc1(s0, u0);
        acc1(s1, u1);
    }
    if (e < end) { int s0 = col[e]; acc1(s0, xpack[s0]); }

    float* o = agg + (size_t)n * kAS;
    #pragma unroll
    for (int i = 0; i < 8; i++) o[i]      = aR[i];
    #pragma unroll
    for (int i = 0; i < 8; i++) o[8 + i]  = aU[i];
    #pragma unroll
    for (int i = 0; i < 8; i++) o[16 + i] = aP[i];
    o[24] = cR;  o[25] = cU;  o[26] = cP;
    o[27] = 0.f; o[28] = 0.f; o[29] = 0.f; o[30] = 0.f; o[31] = 0.f;
}

// ---------- dense via MFMA: one wave per 16 nodes ----------
// h16x128 = relu(agg16x32 @ fwT^T)  (8 MFMAs) -> LDS (C->A layout round-trip)
// hw16x40 = h16x128 @ W2            (12 MFMAs)
__global__ void __launch_bounds__(256) gcn_dense(const float* __restrict__ agg,
                                                 const unsigned short* __restrict__ fwT,
                                                 const void* __restrict__ W2,
                                                 unsigned short* __restrict__ hw,
                                                 const int* __restrict__ flags) {
    __shared__ __align__(16) unsigned short sfwT[kF][40];     // [feat][k] bf16, row-pad 40
    __shared__ __align__(16) unsigned short sw2T[48][136];    // [class][k] bf16, row-pad 136
    __shared__ __align__(16) unsigned short hbuf[4][16][136]; // per-wave h tile [node][feat]
    int isbf = flags[0];
    int tid = threadIdx.x;
    for (int i = tid; i < kF * 32; i += 256) sfwT[i >> 5][i & 31] = fwT[i];
    for (int i = tid; i < 48 * kF; i += 256) {
        int c = i >> 7, k = i & 127;
        sw2T[c][k] = (c < kC) ? f_to_bf(ldf(W2, k * kC + c, isbf)) : (unsigned short)0;
    }
    __syncthreads();
    int wid = tid >> 6, lane = tid & 63;
    int T = blockIdx.x * 4 + wid;              // 16-node tile id, kN/16 = 6250 exact
    if (T >= kN / 16) return;
    int n0 = T * 16;
    int m = lane & 15, q = lane >> 4;          // m: M/N index, q: quad (K-chunk)

    // A1 frag: A[m][k=q*8+j] from agg row (fp32 -> bf16)
    const float* ar = agg + (size_t)(n0 + m) * kAS + q * 8;
    bf16x8 a1;
    #pragma unroll
    for (int i = 0; i < 8; i++) a1[i] = (short)f_to_bf(ar[i]);

    // layer 1: 8 feature tiles of 16
    f32x4 c1[8];
    #pragma unroll
    for (int t = 0; t < 8; t++) {
        bf16x8 b = *(const bf16x8*)&sfwT[16 * t + m][q * 8];   // B[k][n]: n=lane&15
        f32x4 z = {0.f, 0.f, 0.f, 0.f};
        c1[t] = __builtin_amdgcn_mfma_f32_16x16x32_bf16(a1, b, z, 0, 0, 0);
    }
    // relu; C layout (row=q*4+r -> node, col=m -> feat) into hbuf[node][feat]
    #pragma unroll
    for (int t = 0; t < 8; t++) {
        #pragma unroll
        for (int r = 0; r < 4; r++)
            hbuf[wid][q * 4 + r][16 * t + m] = f_to_bf(fmaxf(c1[t][r], 0.f));
    }
    // layer 2: K=128 (4 steps), N=40 (3 class tiles, last half-masked)
    f32x4 c2[3];
    #pragma unroll
    for (int t = 0; t < 3; t++) { c2[t].x = 0.f; c2[t].y = 0.f; c2[t].z = 0.f; c2[t].w = 0.f; }
    #pragma unroll
    for (int s = 0; s < 4; s++) {
        bf16x8 a2 = *(const bf16x8*)&hbuf[wid][m][s * 32 + q * 8];  // A[m=node][k]
        #pragma unroll
        for (int t = 0; t < 3; t++) {
            bf16x8 b2 = *(const bf16x8*)&sw2T[16 * t + m][s * 32 + q * 8];
            c2[t] = __builtin_amdgcn_mfma_f32_16x16x32_bf16(a2, b2, c2[t], 0, 0, 0);
        }
    }
    // store: col=m -> class, row=q*4+r -> node; 16 lanes -> 32B contiguous
    #pragma unroll
    for (int t = 0; t < 3; t++) {
        int cls = 16 * t + m;
        if (cls < kC) {
            #pragma unroll
            for (int r = 0; r < 4; r++)
                hw[(size_t)(n0 + q * 4 + r) * kC + cls] = f_to_bf(c2[t][r]);
        }
    }
}

// ---------- layer-2 gather: 3 edge-groups x 20 class-lanes per wave ----------
__global__ void __launch_bounds__(256) gcn_gather2(const unsigned int* __restrict__ hw32,
                                                   const int* __restrict__ rp,
                                                   const int* __restrict__ col,
                                                   unsigned int* __restrict__ out,
                                                   const int* __restrict__ flags) {
    int isbf = flags[0];
    int w = (blockIdx.x * 256 + threadIdx.x) >> 6;
    if (w >= kN) return;
    int lane = threadIdx.x & 63;
    int grp = lane / 20;          // 0..2 active, 3 idle
    int c2  = lane % 20;          // class pair
    int beg = rp[w], end = rp[w + 1];
    float ax = 0.f, ay = 0.f;
    if (grp < 3) {
        int e = beg + grp;
        for (; e + 3 < end; e += 6) {
            float2 f0 = bf2_to_f2(hw32[col[e]     * 20 + c2]);
            float2 f1 = bf2_to_f2(hw32[col[e + 3] * 20 + c2]);
            ax += f0.x + f1.x;  ay += f0.y + f1.y;
        }
        if (e < end) {
            float2 f = bf2_to_f2(hw32[col[e] * 20 + c2]);
            ax += f.x; ay += f.y;
        }
    }
    ax += __shfl(ax, lane + 20, 64) + __shfl(ax, lane + 40, 64);
    ay += __shfl(ay, lane + 20, 64) + __shfl(ay, lane + 40, 64);
    if (lane < 20) {
        if (isbf) {
            out[w * 20 + lane] = pack_bf2(ax, ay);
        } else {
            float* of = (float*)out;
            of[w * 40 + 2*lane]     = ax;
            of[w * 40 + 2*lane + 1] = ay;
        }
    }
}

extern "C" void kernel_launch(void* const* d_in, const int* in_sizes, int n_in,
                              void* d_out, int out_size, void* d_ws, size_t ws_size,
                              hipStream_t stream) {
    const void* xr = d_in[0];
    const void* xu = d_in[1];
    const void* xp = d_in[2];
    const int*  ei = (const int*)d_in[3];
    const void* Wr = d_in[4];
    const void* br = d_in[5];
    const void* Wu = d_in[6];
    const void* bu = d_in[7];
    const void* Wp = d_in[8];
    const void* bp = d_in[9];
    const void* W1 = d_in[10];
    const void* W2 = d_in[11];
    (void)in_sizes; (void)n_in; (void)out_size; (void)ws_size;

    char* ws = (char*)d_ws;
    size_t off = 0;
    auto alloc = [&](size_t bytes) -> void* {
        void* p = (void*)(ws + off);
        off = (off + bytes + 255) & ~(size_t)255;
        return p;
    };
    int*            flags = (int*)           alloc(256);
    int*            rp    = (int*)           alloc((size_t)(kN + 1) * 4);
    int*            cnt   = (int*)           alloc((size_t)kN * 4);
    int*            cur   = (int*)           alloc((size_t)kN * 4);
    int*            bs    = (int*)           alloc(128 * 4);
    unsigned short* fwT   = (unsigned short*)alloc(kF * 32 * 2);            // 8 KB bf16
    uint4*          xpack = (uint4*)         alloc((size_t)kN * 16);        // 1.6 MB
    int*            col   = (int*)           alloc((size_t)kE * 4);         // 6.4 MB
    unsigned short* hwb   = (unsigned short*)alloc((size_t)kN * kC * 2);    // 8 MB bf16
    float*          agg   = (float*)         alloc((size_t)kN * kAS * 4);   // 12.8 MB

    gcn_sniff<<<1, 64, 0, stream>>>((const unsigned int*)W1, ei, flags);
    gcn_zero_i32<<<(kN + 255) / 256, 256, 0, stream>>>(cnt, kN);
    gcn_fuse<<<1, 128, 0, stream>>>(Wr, br, Wu, bu, Wp, bp, W1, fwT, flags);
    gcn_pack<<<(kN + 255) / 256, 256, 0, stream>>>(xr, xu, xp, xpack, flags);
    gcn_hist<<<(kE + 255) / 256, 256, 0, stream>>>(ei, cnt, flags);
    gcn_scan1<<<kSB, 256, 0, stream>>>(cnt, bs);
    gcn_scan2<<<1, 128, 0, stream>>>(bs, rp);
    gcn_scan3<<<kSB, 256, 0, stream>>>(cnt, bs, rp, cur);
    gcn_fill<<<2048, 256, 0, stream>>>(ei, cur, col, flags);
    GCN_2190433321521_kernel<<<(kN + 255) / 256, 256, 0, stream>>>(xpack, rp, col, agg);
    gcn_dense<<<(kN / 16 + 3) / 4, 256, 0, stream>>>(agg, fwT, W2, hwb, flags);
    gcn_gather2<<<(kN * 64 + 255) / 256, 256, 0, stream>>>((const unsigned int*)hwb, rp, col,
                                                           (unsigned int*)d_out, flags);
}